// Round 3
// baseline (357.868 us; speedup 1.0000x reference)
//
#include <hip/hip_runtime.h>
#include <hip/hip_bf16.h>

typedef __attribute__((ext_vector_type(8))) short short8;
typedef __attribute__((ext_vector_type(4))) float f32x4;

#define BQ 8
#define SEQ 4096
#define CH 512
#define NHD 8
#define HD 64
#define K3C 1536
#define MTOK 32768
#define NSPL 8

__device__ __forceinline__ float bfu2f(unsigned int u) {
  u <<= 16;
  float f;
  __builtin_memcpy(&f, &u, 4);
  return f;
}
__device__ __forceinline__ unsigned short f2bfu(float x) {
  __hip_bfloat16 h = __float2bfloat16(x);
  unsigned short u;
  __builtin_memcpy(&u, &h, 2);
  return u;
}
__device__ __forceinline__ void unpack8(const uint4 u, float* dst) {
  dst[0] = bfu2f(u.x & 0xffffu); dst[1] = bfu2f(u.x >> 16);
  dst[2] = bfu2f(u.y & 0xffffu); dst[3] = bfu2f(u.y >> 16);
  dst[4] = bfu2f(u.z & 0xffffu); dst[5] = bfu2f(u.z >> 16);
  dst[6] = bfu2f(u.w & 0xffffu); dst[7] = bfu2f(u.w >> 16);
}

__device__ __forceinline__ void gload_lds16(const void* g, void* l) {
  __builtin_amdgcn_global_load_lds(
      (const __attribute__((address_space(1))) unsigned int*)g,
      (__attribute__((address_space(3))) unsigned int*)l, 16, 0, 0);
}

// ---------------- cast kernels ----------------
__global__ __launch_bounds__(256) void cast_f32_bf16(const float* __restrict__ in,
                                                     unsigned short* __restrict__ out, int n4) {
  int stride = gridDim.x * blockDim.x;
  for (int i = blockIdx.x * blockDim.x + threadIdx.x; i < n4; i += stride) {
    float4 v = reinterpret_cast<const float4*>(in)[i];
    ushort4 o;
    o.x = f2bfu(v.x); o.y = f2bfu(v.y); o.z = f2bfu(v.z); o.w = f2bfu(v.w);
    reinterpret_cast<ushort4*>(out)[i] = o;
  }
}

// in: f32 [R][Cc] row-major -> out: bf16 [Cc][R]
__global__ __launch_bounds__(256) void transpose_cast(const float* __restrict__ in,
                                                      unsigned short* __restrict__ out,
                                                      int R, int Cc) {
  __shared__ float tile[32][33];
  const int tx = threadIdx.x, ty = threadIdx.y;  // 32 x 8
  const int c0 = blockIdx.x * 32, r0 = blockIdx.y * 32;
  #pragma unroll
  for (int dy = 0; dy < 32; dy += 8)
    tile[ty + dy][tx] = in[(size_t)(r0 + ty + dy) * Cc + (c0 + tx)];
  __syncthreads();
  #pragma unroll
  for (int dy = 0; dy < 32; dy += 8)
    out[(size_t)(c0 + ty + dy) * R + (r0 + tx)] = f2bfu(tile[tx][ty + dy]);
}

// ---------------- 256x256 tile, BK=32, 4-ring, reg-pipelined MFMA GEMM ----------------
// C = A[M][K] * Bt[N][K]^T.  LDS ring: 4 x (A 256x32 + B 256x32) bf16 = 128 KB.
// LDS row = 64 B = 4 slots of 16 B, swizzled: slot(row,kgrp) = kgrp ^ (row&3).
// Stage (global_load_lds linear dest): lane l -> row rbase+(l>>2), slot l&3;
//   pre-swizzled global col = ((l&3)^((l>>2)&3))*8 elems.
// Per tile t (2 phases, 16 MFMA each): stage tile t+2 (A in ph0, B in ph1);
// fragments for phase P+1 ds_read during phase P, retired by counted lgkmcnt(8);
// ONE barrier + ONE vmcnt(4) per tile (at ph1, before reading tile t+1's buffer).
#define STAGE_OP(src, rc0, kt, base) do {                                         \
    _Pragma("unroll")                                                             \
    for (int j_ = 0; j_ < 2; ++j_) {                                              \
      const int rbase_ = (wave * 2 + j_) * 16;                                    \
      const unsigned short* g_ = (src) + (size_t)((rc0) + rbase_ + (lane >> 2)) * Kk + \
                                 (kt) + (((lane & 3) ^ ((lane >> 2) & 3)) << 3);  \
      gload_lds16(g_, (base) + rbase_ * 64);                                      \
    }                                                                             \
  } while (0)

#define DSREAD(buf, qa, R) do {                                                   \
    const char* bA_ = (buf);                                                      \
    const char* bB_ = (buf) + 16384;                                              \
    _Pragma("unroll")                                                             \
    for (int fr_ = 0; fr_ < 4; ++fr_) {                                           \
      const int r_ = wr * 128 + (qa) * 64 + fr_ * 16 + l15;                       \
      R[fr_] = *reinterpret_cast<const short8*>(bA_ + r_ * 64 + ((lg ^ (r_ & 3)) << 4)); \
    }                                                                             \
    _Pragma("unroll")                                                             \
    for (int fc_ = 0; fc_ < 4; ++fc_) {                                           \
      const int n_ = wc * 64 + fc_ * 16 + l15;                                    \
      R[4 + fc_] = *reinterpret_cast<const short8*>(bB_ + n_ * 64 + ((lg ^ (n_ & 3)) << 4)); \
    }                                                                             \
  } while (0)

#define MFMA16(qa, R) do {                                                        \
    __builtin_amdgcn_s_setprio(1);                                                \
    _Pragma("unroll")                                                             \
    for (int fr_ = 0; fr_ < 4; ++fr_)                                             \
      _Pragma("unroll")                                                           \
      for (int fc_ = 0; fc_ < 4; ++fc_)                                           \
        acc[qa][fr_][fc_] = __builtin_amdgcn_mfma_f32_16x16x32_bf16(              \
            R[fr_], R[4 + fc_], acc[qa][fr_][fc_], 0, 0, 0);                      \
    __builtin_amdgcn_s_setprio(0);                                                \
  } while (0)

template <bool OUT_BF16>
__global__ __launch_bounds__(512, 2) void gemm256(const unsigned short* __restrict__ A,
                                                  const unsigned short* __restrict__ Bt,
                                                  void* __restrict__ Cout,
                                                  const float* __restrict__ bias,
                                                  int M, int Nn, int Kk, int nbx) {
  __shared__ __align__(16) char lds[131072];
  const int nwg = gridDim.x;
  int wg = blockIdx.x;
  wg = (wg & 7) * (nwg >> 3) + (wg >> 3);  // XCD swizzle (nwg % 8 == 0)
  const int bx = wg % nbx, by = wg / nbx;
  const int m0 = by * 256, n0 = bx * 256;

  const int tid = threadIdx.x, wave = tid >> 6, lane = tid & 63;
  const int wr = wave >> 2, wc = wave & 3;
  const int l15 = lane & 15, lg = lane >> 4;
  const int T = Kk >> 5;

  f32x4 acc[2][4][4] = {};
  short8 RA[8], RB[8];

  // prologue: stage tiles 0 and 1
  STAGE_OP(A, m0, 0, lds);
  STAGE_OP(Bt, n0, 0, lds + 16384);
  STAGE_OP(A, m0, 32, lds + 32768);
  STAGE_OP(Bt, n0, 32, lds + 32768 + 16384);
  asm volatile("s_waitcnt vmcnt(4)" ::: "memory");  // tile 0 landed
  __builtin_amdgcn_s_barrier();
  DSREAD(lds, 0, RA);

  for (int t = 0; t < T; ++t) {
    char* bufc = lds + (size_t)(t & 3) * 32768;
    char* bufn = lds + (size_t)((t + 1) & 3) * 32768;
    char* bufs = lds + (size_t)((t + 2) & 3) * 32768;
    const int kt2 = (t + 2) << 5;
    // ---- phase 0: compute (t,0) with RA, load (t,1) frags into RB ----
    if (t < T - 2) STAGE_OP(A, m0, kt2, bufs);
    DSREAD(bufc, 1, RB);
    asm volatile("s_waitcnt lgkmcnt(8)" ::: "memory");  // RA ready, RB in flight
    __builtin_amdgcn_sched_barrier(0);
    MFMA16(0, RA);
    // ---- phase 1: compute (t,1) with RB, load (t+1,0) frags into RA ----
    if (t < T - 2) {
      STAGE_OP(Bt, n0, kt2, bufs + 16384);
      asm volatile("s_waitcnt vmcnt(4)" ::: "memory");  // tile t+1 landed
    } else if (t == T - 2) {
      asm volatile("s_waitcnt vmcnt(0)" ::: "memory");
    }
    if (t < T - 1) {
      __builtin_amdgcn_s_barrier();
      DSREAD(bufn, 0, RA);
      asm volatile("s_waitcnt lgkmcnt(8)" ::: "memory");
      __builtin_amdgcn_sched_barrier(0);
      MFMA16(1, RB);
    } else {
      asm volatile("s_waitcnt lgkmcnt(0)" ::: "memory");
      __builtin_amdgcn_sched_barrier(0);
      MFMA16(1, RB);
    }
  }

  // epilogue
  #pragma unroll
  for (int qa = 0; qa < 2; ++qa)
    #pragma unroll
    for (int fr = 0; fr < 4; ++fr)
      #pragma unroll
      for (int fc = 0; fc < 4; ++fc) {
        const int row0 = m0 + wr * 128 + qa * 64 + fr * 16 + lg * 4;
        const int col = n0 + wc * 64 + fc * 16 + l15;
        #pragma unroll
        for (int v = 0; v < 4; ++v) {
          const float val = acc[qa][fr][fc][v];
          if (OUT_BF16) {
            reinterpret_cast<unsigned short*>(Cout)[(size_t)(row0 + v) * Nn + col] = f2bfu(val);
          } else {
            reinterpret_cast<float*>(Cout)[(size_t)(row0 + v) * Nn + col] = val + bias[col];
          }
        }
      }
}

// ---------------- attention partials: raw q.kT and sumsq norms ----------------
__global__ __launch_bounds__(256) void attn_partial(const unsigned short* __restrict__ qkv,
                                                    float* __restrict__ rawp,
                                                    float* __restrict__ normp) {
  const int blk = blockIdx.x;
  const int bh = blk >> 3, s = blk & 7;
  const int b = bh >> 3, h = bh & 7;
  __shared__ float QL[64][68];
  __shared__ float KL[64][68];
  const int tid = threadIdx.x;
  const int tx = tid & 15, ty = tid >> 4;
  float racc[4][4] = {};
  float sq[4] = {0.f, 0.f, 0.f, 0.f}, sk[4] = {0.f, 0.f, 0.f, 0.f};

  for (int chunk = 0; chunk < 8; ++chunk) {
    const int nbase = b * SEQ + s * 512 + chunk * 64;
    __syncthreads();
    #pragma unroll
    for (int l = 0; l < 2; ++l) {
      const int cidx = tid * 2 + l;
      const int r = cidx >> 3, off = (cidx & 7) * 8;
      const size_t rowoff = (size_t)(nbase + r) * K3C;
      uint4 uq = *reinterpret_cast<const uint4*>(qkv + rowoff + h * 64 + off);
      uint4 uk = *reinterpret_cast<const uint4*>(qkv + rowoff + 512 + h * 64 + off);
      unpack8(uq, &QL[r][off]);
      unpack8(uk, &KL[r][off]);
    }
    __syncthreads();
    for (int n = 0; n < 64; ++n) {
      float4 qv = *reinterpret_cast<const float4*>(&QL[n][ty * 4]);
      float4 kv = *reinterpret_cast<const float4*>(&KL[n][tx * 4]);
      float qa[4] = {qv.x, qv.y, qv.z, qv.w};
      float ka[4] = {kv.x, kv.y, kv.z, kv.w};
      #pragma unroll
      for (int i = 0; i < 4; ++i)
        #pragma unroll
        for (int j = 0; j < 4; ++j)
          racc[i][j] = fmaf(qa[i], ka[j], racc[i][j]);
      if (tx == 0) {
        #pragma unroll
        for (int i = 0; i < 4; ++i) sq[i] = fmaf(qa[i], qa[i], sq[i]);
      }
      if (ty == 0) {
        #pragma unroll
        for (int j = 0; j < 4; ++j) sk[j] = fmaf(ka[j], ka[j], sk[j]);
      }
    }
  }
  float* rp = rawp + ((size_t)s * 64 + bh) * 4096;
  #pragma unroll
  for (int i = 0; i < 4; ++i)
    #pragma unroll
    for (int j = 0; j < 4; ++j)
      rp[(ty * 4 + i) * 64 + tx * 4 + j] = racc[i][j];
  float* np = normp + ((size_t)s * 64 + bh) * 128;
  if (tx == 0) {
    #pragma unroll
    for (int i = 0; i < 4; ++i) np[ty * 4 + i] = sq[i];
  }
  if (ty == 0) {
    #pragma unroll
    for (int j = 0; j < 4; ++j) np[64 + tx * 4 + j] = sk[j];
  }
}

// ---------------- finalize: reduce partials, normalize, softmax ----------------
__global__ __launch_bounds__(64) void attn_finalize(const float* __restrict__ rawp,
                                                    const float* __restrict__ normp,
                                                    const float* __restrict__ temperature,
                                                    unsigned short* __restrict__ attnP) {
  const int bh = blockIdx.x, h = bh & 7;
  const int d = threadIdx.x;
  float nq = 0.f, nk = 0.f;
  for (int s = 0; s < NSPL; ++s) {
    nq += normp[((size_t)s * 64 + bh) * 128 + d];
    nk += normp[((size_t)s * 64 + bh) * 128 + 64 + d];
  }
  nq = fmaxf(sqrtf(nq), 1e-12f);
  nk = fmaxf(sqrtf(nk), 1e-12f);
  const float t = temperature[h];
  for (int c = 0; c < 64; ++c) {
    float r = 0.f;
    for (int s = 0; s < NSPL; ++s)
      r += rawp[((size_t)s * 64 + bh) * 4096 + c * 64 + d];
    const float nqc = __shfl(nq, c);
    float v = r * t / (nqc * nk);
    float m = v;
    #pragma unroll
    for (int off = 32; off > 0; off >>= 1) m = fmaxf(m, __shfl_xor(m, off));
    float e = __expf(v - m);
    float ssum = e;
    #pragma unroll
    for (int off = 32; off > 0; off >>= 1) ssum += __shfl_xor(ssum, off);
    attnP[(size_t)bh * 4096 + c * 64 + d] = f2bfu(e / ssum);
  }
}

// ---------------- y[n][h*64+c] = sum_d P[c][d] * V[n][d] ----------------
__global__ __launch_bounds__(256) void pv_kernel(const unsigned short* __restrict__ qkv,
                                                 const unsigned short* __restrict__ attnP,
                                                 unsigned short* __restrict__ y) {
  const int nt = blockIdx.x, h = blockIdx.y, b = blockIdx.z;
  const int bh = b * 8 + h;
  __shared__ float PL[64][68];
  __shared__ float VL[64][68];
  const int tid = threadIdx.x;
  const int tx = tid & 15, ty = tid >> 4;
  #pragma unroll
  for (int l = 0; l < 2; ++l) {
    const int cidx = tid * 2 + l;
    const int r = cidx >> 3, off = (cidx & 7) * 8;
    uint4 up = *reinterpret_cast<const uint4*>(attnP + (size_t)bh * 4096 + r * 64 + off);
    uint4 uv = *reinterpret_cast<const uint4*>(
        qkv + (size_t)(b * SEQ + nt * 64 + r) * K3C + 1024 + h * 64 + off);
    unpack8(up, &PL[r][off]);
    unpack8(uv, &VL[r][off]);
  }
  __syncthreads();
  float acc[4][4] = {};
  for (int d4 = 0; d4 < 64; d4 += 4) {
    float4 vv[4], pp[4];
    #pragma unroll
    for (int i = 0; i < 4; ++i) vv[i] = *reinterpret_cast<const float4*>(&VL[ty * 4 + i][d4]);
    #pragma unroll
    for (int j = 0; j < 4; ++j) pp[j] = *reinterpret_cast<const float4*>(&PL[tx * 4 + j][d4]);
    #pragma unroll
    for (int i = 0; i < 4; ++i)
      #pragma unroll
      for (int j = 0; j < 4; ++j)
        acc[i][j] += vv[i].x * pp[j].x + vv[i].y * pp[j].y + vv[i].z * pp[j].z + vv[i].w * pp[j].w;
  }
  #pragma unroll
  for (int i = 0; i < 4; ++i) {
    ushort4 o;
    o.x = f2bfu(acc[i][0]); o.y = f2bfu(acc[i][1]);
    o.z = f2bfu(acc[i][2]); o.w = f2bfu(acc[i][3]);
    *reinterpret_cast<ushort4*>(
        &y[(size_t)(b * SEQ + nt * 64 + ty * 4 + i) * CH + h * 64 + tx * 4]) = o;
  }
}

extern "C" void kernel_launch(void* const* d_in, const int* in_sizes, int n_in,
                              void* d_out, int out_size, void* d_ws, size_t ws_size,
                              hipStream_t stream) {
  const float* x = (const float*)d_in[0];
  const float* Wqkv = (const float*)d_in[2];
  const float* temp = (const float*)d_in[3];
  const float* Wproj = (const float*)d_in[4];
  const float* bproj = (const float*)d_in[5];
  float* out = (float*)d_out;

  char* w = (char*)d_ws;
  unsigned short* xb = (unsigned short*)w;    w += (size_t)MTOK * CH * 2;
  unsigned short* wqT = (unsigned short*)w;   w += (size_t)K3C * CH * 2;
  unsigned short* wpT = (unsigned short*)w;   w += (size_t)CH * CH * 2;
  unsigned short* qkvb = (unsigned short*)w;  w += (size_t)MTOK * K3C * 2;
  unsigned short* yb = (unsigned short*)w;    w += (size_t)MTOK * CH * 2;
  float* rawp = (float*)w;                    w += (size_t)NSPL * 64 * 4096 * 4;
  float* normp = (float*)w;                   w += (size_t)NSPL * 64 * 128 * 4;
  unsigned short* attnP = (unsigned short*)w; w += (size_t)64 * 4096 * 2;

  cast_f32_bf16<<<2048, 256, 0, stream>>>(x, xb, MTOK * CH / 4);
  transpose_cast<<<dim3(K3C / 32, CH / 32), dim3(32, 8), 0, stream>>>(Wqkv, wqT, CH, K3C);
  transpose_cast<<<dim3(CH / 32, CH / 32), dim3(32, 8), 0, stream>>>(Wproj, wpT, CH, CH);
  gemm256<true><<<768, 512, 0, stream>>>(xb, wqT, qkvb, nullptr, MTOK, K3C, CH, 6);
  attn_partial<<<512, 256, 0, stream>>>(qkvb, rawp, normp);
  attn_finalize<<<64, 64, 0, stream>>>(rawp, normp, temp, attnP);
  pv_kernel<<<dim3(SEQ / 64, NHD, BQ), 256, 0, stream>>>(qkvb, attnP, yb);
  gemm256<false><<<256, 512, 0, stream>>>(yb, wpT, out, bproj, MTOK, CH, CH, 2);
}

// Round 4
// 267.501 us; speedup vs baseline: 1.3378x; 1.3378x over previous
//
#include <hip/hip_runtime.h>
#include <hip/hip_bf16.h>

typedef __attribute__((ext_vector_type(8))) short short8;
typedef __attribute__((ext_vector_type(4))) float f32x4;

#define BQ 8
#define SEQ 4096
#define CH 512
#define NHD 8
#define HD 64
#define K3C 1536
#define MTOK 32768
#define NSPL 8

__device__ __forceinline__ float bfu2f(unsigned int u) {
  u <<= 16;
  float f;
  __builtin_memcpy(&f, &u, 4);
  return f;
}
__device__ __forceinline__ unsigned short f2bfu(float x) {
  __hip_bfloat16 h = __float2bfloat16(x);
  unsigned short u;
  __builtin_memcpy(&u, &h, 2);
  return u;
}
__device__ __forceinline__ void unpack8(const uint4 u, float* dst) {
  dst[0] = bfu2f(u.x & 0xffffu); dst[1] = bfu2f(u.x >> 16);
  dst[2] = bfu2f(u.y & 0xffffu); dst[3] = bfu2f(u.y >> 16);
  dst[4] = bfu2f(u.z & 0xffffu); dst[5] = bfu2f(u.z >> 16);
  dst[6] = bfu2f(u.w & 0xffffu); dst[7] = bfu2f(u.w >> 16);
}

__device__ __forceinline__ void gload_lds16(const void* g, void* l) {
  __builtin_amdgcn_global_load_lds(
      (const __attribute__((address_space(1))) unsigned int*)g,
      (__attribute__((address_space(3))) unsigned int*)l, 16, 0, 0);
}

// ---------------- cast kernels ----------------
__global__ __launch_bounds__(256) void cast_f32_bf16(const float* __restrict__ in,
                                                     unsigned short* __restrict__ out, int n4) {
  int stride = gridDim.x * blockDim.x;
  for (int i = blockIdx.x * blockDim.x + threadIdx.x; i < n4; i += stride) {
    float4 v = reinterpret_cast<const float4*>(in)[i];
    ushort4 o;
    o.x = f2bfu(v.x); o.y = f2bfu(v.y); o.z = f2bfu(v.z); o.w = f2bfu(v.w);
    reinterpret_cast<ushort4*>(out)[i] = o;
  }
}

// in: f32 [R][Cc] row-major -> out: bf16 [Cc][R]
__global__ __launch_bounds__(256) void transpose_cast(const float* __restrict__ in,
                                                      unsigned short* __restrict__ out,
                                                      int R, int Cc) {
  __shared__ float tile[32][33];
  const int tx = threadIdx.x, ty = threadIdx.y;  // 32 x 8
  const int c0 = blockIdx.x * 32, r0 = blockIdx.y * 32;
  #pragma unroll
  for (int dy = 0; dy < 32; dy += 8)
    tile[ty + dy][tx] = in[(size_t)(r0 + ty + dy) * Cc + (c0 + tx)];
  __syncthreads();
  #pragma unroll
  for (int dy = 0; dy < 32; dy += 8)
    out[(size_t)(c0 + ty + dy) * R + (r0 + tx)] = f2bfu(tile[tx][ty + dy]);
}

// ---------------- 256x256 tile, BK=64, m201-style 4-phase MFMA GEMM ----------------
// C = A[M][K] * Bt[N][K]^T.  LDS dbuf: 2 x (A 256x64 + B 256x64) bf16 = 128 KB.
// Rows are 128 B = 8 slots of 16 B, swizzled slot(row,kgrp) = kgrp ^ (row&7)
// (verified zero-conflict in round 2).  Stage via global_load_lds, linear dest,
// pre-swizzled global source col = ((l&7)^(l>>3))*8 elems.
// Phase q computes quadrant: q0:(a0,b0) q1:(a0,b1) q2:(a1,b1) q3:(a1,b0).
// A-frags live 2 phases, both B-sets live all 4 -> 24 ds_read_b128/wave/tile.
// Stage schedule into next buf: q0:{A0,B0} q1:{B1} q2:{A1} q3:{}  (4,2,2,0 loads)
// vmcnt per phase {6,6,8,4}: guarantees each half lands >=1 trailing barrier
// before its first pre-barrier read (A0,B0@q0; B1@q1; A1@q2 of next tile).
template <bool OUT_BF16>
__global__ __launch_bounds__(512, 2) void gemm256(const unsigned short* __restrict__ A,
                                                  const unsigned short* __restrict__ Bt,
                                                  void* __restrict__ Cout,
                                                  const float* __restrict__ bias,
                                                  int M, int Nn, int Kk, int nbx) {
  __shared__ __align__(16) char lds[131072];
  const int nwg = gridDim.x;
  int wg = blockIdx.x;
  wg = (wg & 7) * (nwg >> 3) + (wg >> 3);  // XCD swizzle (nwg % 8 == 0)
  const int bx = wg % nbx, by = wg / nbx;
  const int m0 = by * 256, n0 = bx * 256;

  const int tid = threadIdx.x, wave = tid >> 6, lane = tid & 63;
  const int wr = wave >> 2, wc = wave & 3;
  const int l15 = lane & 15, lg = lane >> 4;
  const int T = Kk >> 6;

  f32x4 acc[2][4][2][2] = {};
  short8 af[8], b0[4], b1[4];

  auto stageh = [&](int h, int kt, char* buf) {
    const bool isB = (h == 1 || h == 2);
    const unsigned short* src = isB ? Bt : A;
    const int rc0 = isB ? n0 : m0;
    const int rhalf = (h >= 2) ? 128 : 0;
    char* base = buf + (isB ? 32768 : 0);
    #pragma unroll
    for (int j = 0; j < 2; ++j) {
      const int rbase = rhalf + (wave * 2 + j) * 8;
      const unsigned short* g = src + (size_t)(rc0 + rbase + (lane >> 3)) * Kk + kt +
                                (((lane & 7) ^ (lane >> 3)) << 3);
      gload_lds16(g, base + rbase * 128);
    }
  };

  auto dsA = [&](int qa, const char* bufc) {
    #pragma unroll
    for (int fr = 0; fr < 4; ++fr)
      #pragma unroll
      for (int ks = 0; ks < 2; ++ks) {
        const int r = wr * 64 + qa * 128 + fr * 16 + l15;
        const int slot = ((ks << 2) + lg) ^ (r & 7);
        af[fr * 2 + ks] = *reinterpret_cast<const short8*>(bufc + r * 128 + (slot << 4));
      }
  };
  auto dsB = [&](int qb, const char* bufc, short8* bset) {
    #pragma unroll
    for (int fc = 0; fc < 2; ++fc)
      #pragma unroll
      for (int ks = 0; ks < 2; ++ks) {
        const int n = wc * 32 + qb * 128 + fc * 16 + l15;
        const int slot = ((ks << 2) + lg) ^ (n & 7);
        bset[fc * 2 + ks] =
            *reinterpret_cast<const short8*>(bufc + 32768 + n * 128 + (slot << 4));
      }
  };
  auto mfma16 = [&](int qa, int qb, const short8* bset) {
    __builtin_amdgcn_s_setprio(1);
    #pragma unroll
    for (int fr = 0; fr < 4; ++fr)
      #pragma unroll
      for (int fc = 0; fc < 2; ++fc)
        #pragma unroll
        for (int ks = 0; ks < 2; ++ks)
          acc[qa][fr][qb][fc] = __builtin_amdgcn_mfma_f32_16x16x32_bf16(
              af[fr * 2 + ks], bset[fc * 2 + ks], acc[qa][fr][qb][fc], 0, 0, 0);
    __builtin_amdgcn_s_setprio(0);
  };

  // prologue: stage all 4 halves of K-tile 0
  stageh(0, 0, lds); stageh(1, 0, lds); stageh(2, 0, lds); stageh(3, 0, lds);
  asm volatile("s_waitcnt vmcnt(0)" ::: "memory");
  __builtin_amdgcn_s_barrier();

  for (int t = 0; t < T - 1; ++t) {
    char* bufc = lds + ((t & 1) << 16);
    char* bufn = lds + (((t + 1) & 1) << 16);
    const int ktn = (t + 1) << 6;

    // ---- phase 0: quadrant (a0,b0); read A0,B0; stage A0',B0' ----
    dsA(0, bufc);
    dsB(0, bufc, b0);
    stageh(0, ktn, bufn);
    stageh(1, ktn, bufn);
    __builtin_amdgcn_sched_barrier(0);
    asm volatile("s_waitcnt vmcnt(6)" ::: "memory");
    __builtin_amdgcn_s_barrier();
    asm volatile("s_waitcnt lgkmcnt(0)" ::: "memory");
    mfma16(0, 0, b0);
    __builtin_amdgcn_s_barrier();

    // ---- phase 1: quadrant (a0,b1); read B1; stage B1' ----
    dsB(1, bufc, b1);
    stageh(2, ktn, bufn);
    __builtin_amdgcn_sched_barrier(0);
    asm volatile("s_waitcnt vmcnt(6)" ::: "memory");
    __builtin_amdgcn_s_barrier();
    asm volatile("s_waitcnt lgkmcnt(0)" ::: "memory");
    mfma16(0, 1, b1);
    __builtin_amdgcn_s_barrier();

    // ---- phase 2: quadrant (a1,b1); read A1; stage A1' ----
    dsA(1, bufc);
    stageh(3, ktn, bufn);
    __builtin_amdgcn_sched_barrier(0);
    asm volatile("s_waitcnt vmcnt(8)" ::: "memory");
    __builtin_amdgcn_s_barrier();
    asm volatile("s_waitcnt lgkmcnt(0)" ::: "memory");
    mfma16(1, 1, b1);
    __builtin_amdgcn_s_barrier();

    // ---- phase 3: quadrant (a1,b0); no reads, no stage ----
    asm volatile("s_waitcnt vmcnt(4)" ::: "memory");
    __builtin_amdgcn_s_barrier();
    mfma16(1, 0, b0);
    __builtin_amdgcn_s_barrier();
  }

  // last K-tile: everything resident, no staging
  asm volatile("s_waitcnt vmcnt(0)" ::: "memory");
  __builtin_amdgcn_s_barrier();
  {
    const char* bufc = lds + (((T - 1) & 1) << 16);
    dsA(0, bufc);
    dsB(0, bufc, b0);
    asm volatile("s_waitcnt lgkmcnt(0)" ::: "memory");
    mfma16(0, 0, b0);
    dsB(1, bufc, b1);
    asm volatile("s_waitcnt lgkmcnt(0)" ::: "memory");
    mfma16(0, 1, b1);
    dsA(1, bufc);
    asm volatile("s_waitcnt lgkmcnt(0)" ::: "memory");
    mfma16(1, 1, b1);
    mfma16(1, 0, b0);
  }

  // epilogue
  #pragma unroll
  for (int qa = 0; qa < 2; ++qa)
    #pragma unroll
    for (int fr = 0; fr < 4; ++fr)
      #pragma unroll
      for (int qb = 0; qb < 2; ++qb)
        #pragma unroll
        for (int fc = 0; fc < 2; ++fc) {
          const int row0 = m0 + wr * 64 + qa * 128 + fr * 16 + lg * 4;
          const int col = n0 + wc * 32 + qb * 128 + fc * 16 + l15;
          #pragma unroll
          for (int v = 0; v < 4; ++v) {
            const float val = acc[qa][fr][qb][fc][v];
            if (OUT_BF16) {
              reinterpret_cast<unsigned short*>(Cout)[(size_t)(row0 + v) * Nn + col] = f2bfu(val);
            } else {
              reinterpret_cast<float*>(Cout)[(size_t)(row0 + v) * Nn + col] = val + bias[col];
            }
          }
        }
}

// ---------------- attention partials: raw q.kT and sumsq norms ----------------
__global__ __launch_bounds__(256) void attn_partial(const unsigned short* __restrict__ qkv,
                                                    float* __restrict__ rawp,
                                                    float* __restrict__ normp) {
  const int blk = blockIdx.x;
  const int bh = blk >> 3, s = blk & 7;
  const int b = bh >> 3, h = bh & 7;
  __shared__ float QL[64][68];
  __shared__ float KL[64][68];
  const int tid = threadIdx.x;
  const int tx = tid & 15, ty = tid >> 4;
  float racc[4][4] = {};
  float sq[4] = {0.f, 0.f, 0.f, 0.f}, sk[4] = {0.f, 0.f, 0.f, 0.f};

  for (int chunk = 0; chunk < 8; ++chunk) {
    const int nbase = b * SEQ + s * 512 + chunk * 64;
    __syncthreads();
    #pragma unroll
    for (int l = 0; l < 2; ++l) {
      const int cidx = tid * 2 + l;
      const int r = cidx >> 3, off = (cidx & 7) * 8;
      const size_t rowoff = (size_t)(nbase + r) * K3C;
      uint4 uq = *reinterpret_cast<const uint4*>(qkv + rowoff + h * 64 + off);
      uint4 uk = *reinterpret_cast<const uint4*>(qkv + rowoff + 512 + h * 64 + off);
      unpack8(uq, &QL[r][off]);
      unpack8(uk, &KL[r][off]);
    }
    __syncthreads();
    for (int n = 0; n < 64; ++n) {
      float4 qv = *reinterpret_cast<const float4*>(&QL[n][ty * 4]);
      float4 kv = *reinterpret_cast<const float4*>(&KL[n][tx * 4]);
      float qa[4] = {qv.x, qv.y, qv.z, qv.w};
      float ka[4] = {kv.x, kv.y, kv.z, kv.w};
      #pragma unroll
      for (int i = 0; i < 4; ++i)
        #pragma unroll
        for (int j = 0; j < 4; ++j)
          racc[i][j] = fmaf(qa[i], ka[j], racc[i][j]);
      if (tx == 0) {
        #pragma unroll
        for (int i = 0; i < 4; ++i) sq[i] = fmaf(qa[i], qa[i], sq[i]);
      }
      if (ty == 0) {
        #pragma unroll
        for (int j = 0; j < 4; ++j) sk[j] = fmaf(ka[j], ka[j], sk[j]);
      }
    }
  }
  float* rp = rawp + ((size_t)s * 64 + bh) * 4096;
  #pragma unroll
  for (int i = 0; i < 4; ++i)
    #pragma unroll
    for (int j = 0; j < 4; ++j)
      rp[(ty * 4 + i) * 64 + tx * 4 + j] = racc[i][j];
  float* np = normp + ((size_t)s * 64 + bh) * 128;
  if (tx == 0) {
    #pragma unroll
    for (int i = 0; i < 4; ++i) np[ty * 4 + i] = sq[i];
  }
  if (ty == 0) {
    #pragma unroll
    for (int j = 0; j < 4; ++j) np[64 + tx * 4 + j] = sk[j];
  }
}

// ---------------- finalize: reduce partials, normalize, softmax ----------------
__global__ __launch_bounds__(64) void attn_finalize(const float* __restrict__ rawp,
                                                    const float* __restrict__ normp,
                                                    const float* __restrict__ temperature,
                                                    unsigned short* __restrict__ attnP) {
  const int bh = blockIdx.x, h = bh & 7;
  const int d = threadIdx.x;
  float nq = 0.f, nk = 0.f;
  for (int s = 0; s < NSPL; ++s) {
    nq += normp[((size_t)s * 64 + bh) * 128 + d];
    nk += normp[((size_t)s * 64 + bh) * 128 + 64 + d];
  }
  nq = fmaxf(sqrtf(nq), 1e-12f);
  nk = fmaxf(sqrtf(nk), 1e-12f);
  const float t = temperature[h];
  for (int c = 0; c < 64; ++c) {
    float r = 0.f;
    for (int s = 0; s < NSPL; ++s)
      r += rawp[((size_t)s * 64 + bh) * 4096 + c * 64 + d];
    const float nqc = __shfl(nq, c);
    float v = r * t / (nqc * nk);
    float m = v;
    #pragma unroll
    for (int off = 32; off > 0; off >>= 1) m = fmaxf(m, __shfl_xor(m, off));
    float e = __expf(v - m);
    float ssum = e;
    #pragma unroll
    for (int off = 32; off > 0; off >>= 1) ssum += __shfl_xor(ssum, off);
    attnP[(size_t)bh * 4096 + c * 64 + d] = f2bfu(e / ssum);
  }
}

// ---------------- y[n][h*64+c] = sum_d P[c][d] * V[n][d] ----------------
__global__ __launch_bounds__(256) void pv_kernel(const unsigned short* __restrict__ qkv,
                                                 const unsigned short* __restrict__ attnP,
                                                 unsigned short* __restrict__ y) {
  const int nt = blockIdx.x, h = blockIdx.y, b = blockIdx.z;
  const int bh = b * 8 + h;
  __shared__ float PL[64][68];
  __shared__ float VL[64][68];
  const int tid = threadIdx.x;
  const int tx = tid & 15, ty = tid >> 4;
  #pragma unroll
  for (int l = 0; l < 2; ++l) {
    const int cidx = tid * 2 + l;
    const int r = cidx >> 3, off = (cidx & 7) * 8;
    uint4 up = *reinterpret_cast<const uint4*>(attnP + (size_t)bh * 4096 + r * 64 + off);
    uint4 uv = *reinterpret_cast<const uint4*>(
        qkv + (size_t)(b * SEQ + nt * 64 + r) * K3C + 1024 + h * 64 + off);
    unpack8(up, &PL[r][off]);
    unpack8(uv, &VL[r][off]);
  }
  __syncthreads();
  float acc[4][4] = {};
  for (int d4 = 0; d4 < 64; d4 += 4) {
    float4 vv[4], pp[4];
    #pragma unroll
    for (int i = 0; i < 4; ++i) vv[i] = *reinterpret_cast<const float4*>(&VL[ty * 4 + i][d4]);
    #pragma unroll
    for (int j = 0; j < 4; ++j) pp[j] = *reinterpret_cast<const float4*>(&PL[tx * 4 + j][d4]);
    #pragma unroll
    for (int i = 0; i < 4; ++i)
      #pragma unroll
      for (int j = 0; j < 4; ++j)
        acc[i][j] += vv[i].x * pp[j].x + vv[i].y * pp[j].y + vv[i].z * pp[j].z + vv[i].w * pp[j].w;
  }
  #pragma unroll
  for (int i = 0; i < 4; ++i) {
    ushort4 o;
    o.x = f2bfu(acc[i][0]); o.y = f2bfu(acc[i][1]);
    o.z = f2bfu(acc[i][2]); o.w = f2bfu(acc[i][3]);
    *reinterpret_cast<ushort4*>(
        &y[(size_t)(b * SEQ + nt * 64 + ty * 4 + i) * CH + h * 64 + tx * 4]) = o;
  }
}

extern "C" void kernel_launch(void* const* d_in, const int* in_sizes, int n_in,
                              void* d_out, int out_size, void* d_ws, size_t ws_size,
                              hipStream_t stream) {
  const float* x = (const float*)d_in[0];
  const float* Wqkv = (const float*)d_in[2];
  const float* temp = (const float*)d_in[3];
  const float* Wproj = (const float*)d_in[4];
  const float* bproj = (const float*)d_in[5];
  float* out = (float*)d_out;

  char* w = (char*)d_ws;
  unsigned short* xb = (unsigned short*)w;    w += (size_t)MTOK * CH * 2;
  unsigned short* wqT = (unsigned short*)w;   w += (size_t)K3C * CH * 2;
  unsigned short* wpT = (unsigned short*)w;   w += (size_t)CH * CH * 2;
  unsigned short* qkvb = (unsigned short*)w;  w += (size_t)MTOK * K3C * 2;
  unsigned short* yb = (unsigned short*)w;    w += (size_t)MTOK * CH * 2;
  float* rawp = (float*)w;                    w += (size_t)NSPL * 64 * 4096 * 4;
  float* normp = (float*)w;                   w += (size_t)NSPL * 64 * 128 * 4;
  unsigned short* attnP = (unsigned short*)w; w += (size_t)64 * 4096 * 2;

  cast_f32_bf16<<<2048, 256, 0, stream>>>(x, xb, MTOK * CH / 4);
  transpose_cast<<<dim3(K3C / 32, CH / 32), dim3(32, 8), 0, stream>>>(Wqkv, wqT, CH, K3C);
  transpose_cast<<<dim3(CH / 32, CH / 32), dim3(32, 8), 0, stream>>>(Wproj, wpT, CH, CH);
  gemm256<true><<<768, 512, 0, stream>>>(xb, wqT, qkvb, nullptr, MTOK, K3C, CH, 6);
  attn_partial<<<512, 256, 0, stream>>>(qkvb, rawp, normp);
  attn_finalize<<<64, 64, 0, stream>>>(rawp, normp, temp, attnP);
  pv_kernel<<<dim3(SEQ / 64, NHD, BQ), 256, 0, stream>>>(qkvb, attnP, yb);
  gemm256<false><<<256, 512, 0, stream>>>(yb, wpT, out, bproj, MTOK, CH, CH, 2);
}

// Round 5
// 163.361 us; speedup vs baseline: 2.1907x; 1.6375x over previous
//
#include <hip/hip_runtime.h>
#include <hip/hip_bf16.h>

typedef __attribute__((ext_vector_type(8))) short short8;
typedef __attribute__((ext_vector_type(4))) float f32x4;

#define BQ 8
#define SEQ 4096
#define CH 512
#define NHD 8
#define HD 64
#define K3C 1536
#define MTOK 32768
#define NSPL 8

__device__ __forceinline__ float bfu2f(unsigned int u) {
  u <<= 16;
  float f;
  __builtin_memcpy(&f, &u, 4);
  return f;
}
__device__ __forceinline__ unsigned short f2bfu(float x) {
  __hip_bfloat16 h = __float2bfloat16(x);
  unsigned short u;
  __builtin_memcpy(&u, &h, 2);
  return u;
}

__device__ __forceinline__ void gload_lds16(const void* g, void* l) {
  __builtin_amdgcn_global_load_lds(
      (const __attribute__((address_space(1))) unsigned int*)g,
      (__attribute__((address_space(3))) unsigned int*)l, 16, 0, 0);
}

// ---------------- cast kernels ----------------
__global__ __launch_bounds__(256) void cast_f32_bf16(const float* __restrict__ in,
                                                     unsigned short* __restrict__ out, int n4) {
  int stride = gridDim.x * blockDim.x;
  for (int i = blockIdx.x * blockDim.x + threadIdx.x; i < n4; i += stride) {
    float4 v = reinterpret_cast<const float4*>(in)[i];
    ushort4 o;
    o.x = f2bfu(v.x); o.y = f2bfu(v.y); o.z = f2bfu(v.z); o.w = f2bfu(v.w);
    reinterpret_cast<ushort4*>(out)[i] = o;
  }
}

// in: f32 [R][Cc] row-major -> out: bf16 [Cc][R]
__global__ __launch_bounds__(256) void transpose_cast(const float* __restrict__ in,
                                                      unsigned short* __restrict__ out,
                                                      int R, int Cc) {
  __shared__ float tile[32][33];
  const int tx = threadIdx.x, ty = threadIdx.y;  // 32 x 8
  const int c0 = blockIdx.x * 32, r0 = blockIdx.y * 32;
  #pragma unroll
  for (int dy = 0; dy < 32; dy += 8)
    tile[ty + dy][tx] = in[(size_t)(r0 + ty + dy) * Cc + (c0 + tx)];
  __syncthreads();
  #pragma unroll
  for (int dy = 0; dy < 32; dy += 8)
    out[(size_t)(c0 + ty + dy) * R + (r0 + tx)] = f2bfu(tile[tx][ty + dy]);
}

// ---------------- 256x256 tile, BK=64, 4-phase MFMA GEMM (round-4 schedule) ----------
// MODE 0: QKV -> scatter epilogue: Q,K transposed to qkT[sel][bh][c][n]; V to vb[bh][n][d]
// MODE 1: proj -> f32 out + bias, row-major
template <int MODE>
__global__ __launch_bounds__(512, 2) void gemm256(const unsigned short* __restrict__ A,
                                                  const unsigned short* __restrict__ Bt,
                                                  void* __restrict__ out0,
                                                  void* __restrict__ out1,
                                                  const float* __restrict__ bias,
                                                  int M, int Nn, int Kk, int nbx) {
  __shared__ __align__(16) char lds[131072];
  const int nwg = gridDim.x;
  int wg = blockIdx.x;
  wg = (wg & 7) * (nwg >> 3) + (wg >> 3);  // XCD swizzle (nwg % 8 == 0)
  const int bx = wg % nbx, by = wg / nbx;
  const int m0 = by * 256, n0 = bx * 256;

  const int tid = threadIdx.x, wave = tid >> 6, lane = tid & 63;
  const int wr = wave >> 2, wc = wave & 3;
  const int l15 = lane & 15, lg = lane >> 4;
  const int T = Kk >> 6;

  f32x4 acc[2][4][2][2] = {};
  short8 af[8], b0[4], b1[4];

  auto stageh = [&](int h, int kt, char* buf) {
    const bool isB = (h == 1 || h == 2);
    const unsigned short* src = isB ? Bt : A;
    const int rc0 = isB ? n0 : m0;
    const int rhalf = (h >= 2) ? 128 : 0;
    char* base = buf + (isB ? 32768 : 0);
    #pragma unroll
    for (int j = 0; j < 2; ++j) {
      const int rbase = rhalf + (wave * 2 + j) * 8;
      const unsigned short* g = src + (size_t)(rc0 + rbase + (lane >> 3)) * Kk + kt +
                                (((lane & 7) ^ (lane >> 3)) << 3);
      gload_lds16(g, base + rbase * 128);
    }
  };

  auto dsA = [&](int qa, const char* bufc) {
    #pragma unroll
    for (int fr = 0; fr < 4; ++fr)
      #pragma unroll
      for (int ks = 0; ks < 2; ++ks) {
        const int r = wr * 64 + qa * 128 + fr * 16 + l15;
        const int slot = ((ks << 2) + lg) ^ (r & 7);
        af[fr * 2 + ks] = *reinterpret_cast<const short8*>(bufc + r * 128 + (slot << 4));
      }
  };
  auto dsB = [&](int qb, const char* bufc, short8* bset) {
    #pragma unroll
    for (int fc = 0; fc < 2; ++fc)
      #pragma unroll
      for (int ks = 0; ks < 2; ++ks) {
        const int n = wc * 32 + qb * 128 + fc * 16 + l15;
        const int slot = ((ks << 2) + lg) ^ (n & 7);
        bset[fc * 2 + ks] =
            *reinterpret_cast<const short8*>(bufc + 32768 + n * 128 + (slot << 4));
      }
  };
  auto mfma16 = [&](int qa, int qb, const short8* bset) {
    __builtin_amdgcn_s_setprio(1);
    #pragma unroll
    for (int fr = 0; fr < 4; ++fr)
      #pragma unroll
      for (int fc = 0; fc < 2; ++fc)
        #pragma unroll
        for (int ks = 0; ks < 2; ++ks)
          acc[qa][fr][qb][fc] = __builtin_amdgcn_mfma_f32_16x16x32_bf16(
              af[fr * 2 + ks], bset[fc * 2 + ks], acc[qa][fr][qb][fc], 0, 0, 0);
    __builtin_amdgcn_s_setprio(0);
  };

  stageh(0, 0, lds); stageh(1, 0, lds); stageh(2, 0, lds); stageh(3, 0, lds);
  asm volatile("s_waitcnt vmcnt(0)" ::: "memory");
  __builtin_amdgcn_s_barrier();

  for (int t = 0; t < T - 1; ++t) {
    char* bufc = lds + ((t & 1) << 16);
    char* bufn = lds + (((t + 1) & 1) << 16);
    const int ktn = (t + 1) << 6;

    dsA(0, bufc);
    dsB(0, bufc, b0);
    stageh(0, ktn, bufn);
    stageh(1, ktn, bufn);
    __builtin_amdgcn_sched_barrier(0);
    asm volatile("s_waitcnt vmcnt(6)" ::: "memory");
    __builtin_amdgcn_s_barrier();
    asm volatile("s_waitcnt lgkmcnt(0)" ::: "memory");
    mfma16(0, 0, b0);
    __builtin_amdgcn_s_barrier();

    dsB(1, bufc, b1);
    stageh(2, ktn, bufn);
    __builtin_amdgcn_sched_barrier(0);
    asm volatile("s_waitcnt vmcnt(6)" ::: "memory");
    __builtin_amdgcn_s_barrier();
    asm volatile("s_waitcnt lgkmcnt(0)" ::: "memory");
    mfma16(0, 1, b1);
    __builtin_amdgcn_s_barrier();

    dsA(1, bufc);
    stageh(3, ktn, bufn);
    __builtin_amdgcn_sched_barrier(0);
    asm volatile("s_waitcnt vmcnt(8)" ::: "memory");
    __builtin_amdgcn_s_barrier();
    asm volatile("s_waitcnt lgkmcnt(0)" ::: "memory");
    mfma16(1, 1, b1);
    __builtin_amdgcn_s_barrier();

    asm volatile("s_waitcnt vmcnt(4)" ::: "memory");
    __builtin_amdgcn_s_barrier();
    mfma16(1, 0, b0);
    __builtin_amdgcn_s_barrier();
  }

  asm volatile("s_waitcnt vmcnt(0)" ::: "memory");
  __builtin_amdgcn_s_barrier();
  {
    const char* bufc = lds + (((T - 1) & 1) << 16);
    dsA(0, bufc);
    dsB(0, bufc, b0);
    asm volatile("s_waitcnt lgkmcnt(0)" ::: "memory");
    mfma16(0, 0, b0);
    dsB(1, bufc, b1);
    asm volatile("s_waitcnt lgkmcnt(0)" ::: "memory");
    mfma16(0, 1, b1);
    dsA(1, bufc);
    asm volatile("s_waitcnt lgkmcnt(0)" ::: "memory");
    mfma16(1, 1, b1);
    mfma16(1, 0, b0);
  }

  // epilogue
  #pragma unroll
  for (int qa = 0; qa < 2; ++qa)
    #pragma unroll
    for (int fr = 0; fr < 4; ++fr)
      #pragma unroll
      for (int qb = 0; qb < 2; ++qb)
        #pragma unroll
        for (int fc = 0; fc < 2; ++fc) {
          const int row0 = m0 + wr * 64 + qa * 128 + fr * 16 + lg * 4;
          const int col = n0 + wc * 32 + qb * 128 + fc * 16 + l15;
          if (MODE == 1) {
            #pragma unroll
            for (int v = 0; v < 4; ++v)
              reinterpret_cast<float*>(out0)[(size_t)(row0 + v) * Nn + col] =
                  acc[qa][fr][qb][fc][v] + bias[col];
          } else {
            const int sel = col >> 9, rem = col & 511, hh = rem >> 6, cc = rem & 63;
            const int bb = row0 >> 12, nseq = row0 & 4095;
            const int bh = bb * 8 + hh;
            if (sel < 2) {
              ushort4 o;
              o.x = f2bfu(acc[qa][fr][qb][fc][0]);
              o.y = f2bfu(acc[qa][fr][qb][fc][1]);
              o.z = f2bfu(acc[qa][fr][qb][fc][2]);
              o.w = f2bfu(acc[qa][fr][qb][fc][3]);
              *reinterpret_cast<ushort4*>(
                  &reinterpret_cast<unsigned short*>(out0)[
                      (((size_t)sel * 4096 + bh * 64 + cc)) * 4096 + nseq]) = o;
            } else {
              #pragma unroll
              for (int v = 0; v < 4; ++v)
                reinterpret_cast<unsigned short*>(out1)[
                    ((size_t)bh * 4096 + nseq + v) * 64 + cc] =
                    f2bfu(acc[qa][fr][qb][fc][v]);
            }
          }
        }
}

// ---------------- attn QK^T via MFMA: rawp[s][bh][c][d] partials + norms ----------------
// qkT: [sel][bh][c][n] bf16 (sel 0=Q,1=K), rows of 4096.
__global__ __launch_bounds__(256) void attn_qk(const unsigned short* __restrict__ qkT,
                                               float* __restrict__ rawp,
                                               float* __restrict__ normp) {
  const int bh = blockIdx.x, s = blockIdx.y;
  const int tid = threadIdx.x, w = tid >> 6, lane = tid & 63;
  const int l15 = lane & 15, lg = lane >> 4;
  const int nbase = s * 512 + w * 128;
  const unsigned short* qrow = qkT + (size_t)(bh * 64) * 4096;
  const unsigned short* krow = qkT + (size_t)(4096 + bh * 64) * 4096;

  __shared__ float red[4][64][64];
  __shared__ float nrm[4][2][64];

  f32x4 acc[4][4] = {};
  float sq[4] = {0.f, 0.f, 0.f, 0.f}, sk[4] = {0.f, 0.f, 0.f, 0.f};

  #pragma unroll
  for (int kc = 0; kc < 2; ++kc) {
    short8 aq[4][2], bk[4][2];
    #pragma unroll
    for (int fr = 0; fr < 4; ++fr)
      #pragma unroll
      for (int ks = 0; ks < 2; ++ks) {
        const size_t off = (size_t)(fr * 16 + l15) * 4096 + nbase + (kc * 2 + ks) * 32 + lg * 8;
        aq[fr][ks] = *reinterpret_cast<const short8*>(&qrow[off]);
        bk[fr][ks] = *reinterpret_cast<const short8*>(&krow[off]);
      }
    #pragma unroll
    for (int ks = 0; ks < 2; ++ks)
      #pragma unroll
      for (int fr = 0; fr < 4; ++fr)
        #pragma unroll
        for (int fc = 0; fc < 4; ++fc)
          acc[fr][fc] = __builtin_amdgcn_mfma_f32_16x16x32_bf16(
              aq[fr][ks], bk[fc][ks], acc[fr][fc], 0, 0, 0);
    #pragma unroll
    for (int fr = 0; fr < 4; ++fr)
      #pragma unroll
      for (int ks = 0; ks < 2; ++ks)
        #pragma unroll
        for (int j = 0; j < 8; ++j) {
          const float fq = bfu2f((unsigned short)aq[fr][ks][j]);
          const float fk = bfu2f((unsigned short)bk[fr][ks][j]);
          sq[fr] = fmaf(fq, fq, sq[fr]);
          sk[fr] = fmaf(fk, fk, sk[fr]);
        }
  }

  // reduce norms across lg groups (lanes l15, l15+16, l15+32, l15+48)
  #pragma unroll
  for (int fr = 0; fr < 4; ++fr) {
    sq[fr] += __shfl_xor(sq[fr], 16); sq[fr] += __shfl_xor(sq[fr], 32);
    sk[fr] += __shfl_xor(sk[fr], 16); sk[fr] += __shfl_xor(sk[fr], 32);
  }
  if (lane < 16) {
    #pragma unroll
    for (int fr = 0; fr < 4; ++fr) {
      nrm[w][0][fr * 16 + lane] = sq[fr];
      nrm[w][1][fr * 16 + lane] = sk[fr];
    }
  }
  // write acc to LDS
  #pragma unroll
  for (int fr = 0; fr < 4; ++fr)
    #pragma unroll
    for (int fc = 0; fc < 4; ++fc)
      #pragma unroll
      for (int v = 0; v < 4; ++v)
        red[w][fr * 16 + lg * 4 + v][fc * 16 + l15] = acc[fr][fc][v];
  __syncthreads();

  const float* rf = &red[0][0][0];
  float* rp = rawp + ((size_t)s * 64 + bh) * 4096;
  for (int i = tid; i < 4096; i += 256)
    rp[i] = rf[i] + rf[4096 + i] + rf[8192 + i] + rf[12288 + i];
  const float* nf = &nrm[0][0][0];
  if (tid < 128) {
    float* np = normp + ((size_t)s * 64 + bh) * 128;
    np[tid] = nf[tid] + nf[128 + tid] + nf[256 + tid] + nf[384 + tid];
  }
}

// ---------------- finalize: reduce partials, normalize, softmax ----------------
__global__ __launch_bounds__(64) void attn_finalize(const float* __restrict__ rawp,
                                                    const float* __restrict__ normp,
                                                    const float* __restrict__ temperature,
                                                    unsigned short* __restrict__ attnP) {
  const int bh = blockIdx.x, c8 = blockIdx.y, h = bh & 7;
  const int d = threadIdx.x;
  float nq = 0.f, nk = 0.f;
  for (int s = 0; s < NSPL; ++s) {
    nq += normp[((size_t)s * 64 + bh) * 128 + d];
    nk += normp[((size_t)s * 64 + bh) * 128 + 64 + d];
  }
  nq = fmaxf(sqrtf(nq), 1e-12f);
  nk = fmaxf(sqrtf(nk), 1e-12f);
  const float t = temperature[h];
  for (int i = 0; i < 8; ++i) {
    const int c = c8 * 8 + i;
    float r = 0.f;
    for (int s = 0; s < NSPL; ++s)
      r += rawp[((size_t)s * 64 + bh) * 4096 + c * 64 + d];
    const float nqc = __shfl(nq, c);
    float v = r * t / (nqc * nk);
    float m = v;
    #pragma unroll
    for (int off = 32; off > 0; off >>= 1) m = fmaxf(m, __shfl_xor(m, off));
    float e = __expf(v - m);
    float ssum = e;
    #pragma unroll
    for (int off = 32; off > 0; off >>= 1) ssum += __shfl_xor(ssum, off);
    attnP[(size_t)bh * 4096 + c * 64 + d] = f2bfu(e / ssum);
  }
}

// ---------------- PV via MFMA: y[b*4096+n][h*64+c] = sum_d P[c,d] * vb[bh][n][d] --------
__global__ __launch_bounds__(256) void pv_mfma(const unsigned short* __restrict__ attnP,
                                               const unsigned short* __restrict__ vb,
                                               unsigned short* __restrict__ y) {
  const int nc = blockIdx.x, bh = blockIdx.y;
  const int b = bh >> 3, h = bh & 7;
  const int tid = threadIdx.x, w = tid >> 6, lane = tid & 63;
  const int l15 = lane & 15, lg = lane >> 4;
  const int n0 = nc * 256 + w * 64;

  short8 ap[4][2], bv[4][2];
  #pragma unroll
  for (int fr = 0; fr < 4; ++fr)
    #pragma unroll
    for (int ks = 0; ks < 2; ++ks)
      ap[fr][ks] = *reinterpret_cast<const short8*>(
          &attnP[(size_t)bh * 4096 + (fr * 16 + l15) * 64 + ks * 32 + lg * 8]);
  #pragma unroll
  for (int fc = 0; fc < 4; ++fc)
    #pragma unroll
    for (int ks = 0; ks < 2; ++ks)
      bv[fc][ks] = *reinterpret_cast<const short8*>(
          &vb[((size_t)bh * 4096 + n0 + fc * 16 + l15) * 64 + ks * 32 + lg * 8]);

  f32x4 acc[4][4] = {};
  #pragma unroll
  for (int ks = 0; ks < 2; ++ks)
    #pragma unroll
    for (int fr = 0; fr < 4; ++fr)
      #pragma unroll
      for (int fc = 0; fc < 4; ++fc)
        acc[fr][fc] = __builtin_amdgcn_mfma_f32_16x16x32_bf16(
            ap[fr][ks], bv[fc][ks], acc[fr][fc], 0, 0, 0);

  #pragma unroll
  for (int fr = 0; fr < 4; ++fr)
    #pragma unroll
    for (int fc = 0; fc < 4; ++fc) {
      const int n = n0 + fc * 16 + l15;
      const int c0 = fr * 16 + lg * 4;
      ushort4 o;
      o.x = f2bfu(acc[fr][fc][0]); o.y = f2bfu(acc[fr][fc][1]);
      o.z = f2bfu(acc[fr][fc][2]); o.w = f2bfu(acc[fr][fc][3]);
      *reinterpret_cast<ushort4*>(
          &y[((size_t)b * 4096 + n) * 512 + h * 64 + c0]) = o;
    }
}

extern "C" void kernel_launch(void* const* d_in, const int* in_sizes, int n_in,
                              void* d_out, int out_size, void* d_ws, size_t ws_size,
                              hipStream_t stream) {
  const float* x = (const float*)d_in[0];
  const float* Wqkv = (const float*)d_in[2];
  const float* temp = (const float*)d_in[3];
  const float* Wproj = (const float*)d_in[4];
  const float* bproj = (const float*)d_in[5];
  float* out = (float*)d_out;

  char* w = (char*)d_ws;
  unsigned short* xb = (unsigned short*)w;    w += (size_t)MTOK * CH * 2;
  unsigned short* wqT = (unsigned short*)w;   w += (size_t)K3C * CH * 2;
  unsigned short* wpT = (unsigned short*)w;   w += (size_t)CH * CH * 2;
  unsigned short* qkT = (unsigned short*)w;   w += (size_t)2 * 64 * 64 * 4096 * 2;
  unsigned short* vb = (unsigned short*)w;    w += (size_t)64 * 4096 * 64 * 2;
  unsigned short* yb = (unsigned short*)w;    w += (size_t)MTOK * CH * 2;
  float* rawp = (float*)w;                    w += (size_t)NSPL * 64 * 4096 * 4;
  float* normp = (float*)w;                   w += (size_t)NSPL * 64 * 128 * 4;
  unsigned short* attnP = (unsigned short*)w; w += (size_t)64 * 4096 * 2;

  cast_f32_bf16<<<2048, 256, 0, stream>>>(x, xb, MTOK * CH / 4);
  transpose_cast<<<dim3(K3C / 32, CH / 32), dim3(32, 8), 0, stream>>>(Wqkv, wqT, CH, K3C);
  transpose_cast<<<dim3(CH / 32, CH / 32), dim3(32, 8), 0, stream>>>(Wproj, wpT, CH, CH);
  gemm256<0><<<768, 512, 0, stream>>>(xb, wqT, qkT, vb, nullptr, MTOK, K3C, CH, 6);
  attn_qk<<<dim3(64, 8), 256, 0, stream>>>(qkT, rawp, normp);
  attn_finalize<<<dim3(64, 8), 64, 0, stream>>>(rawp, normp, temp, attnP);
  pv_mfma<<<dim3(16, 64), 256, 0, stream>>>(attnP, vb, yb);
  gemm256<1><<<256, 512, 0, stream>>>(yb, wpT, out, nullptr, bproj, MTOK, CH, CH, 2);
}

// Round 6
// 157.568 us; speedup vs baseline: 2.2712x; 1.0368x over previous
//
#include <hip/hip_runtime.h>
#include <hip/hip_bf16.h>

typedef __attribute__((ext_vector_type(8))) short short8;
typedef __attribute__((ext_vector_type(4))) float f32x4;

#define BQ 8
#define SEQ 4096
#define CH 512
#define NHD 8
#define HD 64
#define K3C 1536
#define MTOK 32768
#define NSPL 8

__device__ __forceinline__ float bfu2f(unsigned int u) {
  u <<= 16;
  float f;
  __builtin_memcpy(&f, &u, 4);
  return f;
}
__device__ __forceinline__ unsigned short f2bfu(float x) {
  __hip_bfloat16 h = __float2bfloat16(x);
  unsigned short u;
  __builtin_memcpy(&u, &h, 2);
  return u;
}

__device__ __forceinline__ void gload_lds16(const void* g, void* l) {
  __builtin_amdgcn_global_load_lds(
      (const __attribute__((address_space(1))) unsigned int*)g,
      (__attribute__((address_space(3))) unsigned int*)l, 16, 0, 0);
}

// ---------------- cast kernels ----------------
__global__ __launch_bounds__(256) void cast_f32_bf16(const float* __restrict__ in,
                                                     unsigned short* __restrict__ out, int n4) {
  int stride = gridDim.x * blockDim.x;
  for (int i = blockIdx.x * blockDim.x + threadIdx.x; i < n4; i += stride) {
    float4 v = reinterpret_cast<const float4*>(in)[i];
    ushort4 o;
    o.x = f2bfu(v.x); o.y = f2bfu(v.y); o.z = f2bfu(v.z); o.w = f2bfu(v.w);
    reinterpret_cast<ushort4*>(out)[i] = o;
  }
}

// in: f32 [R][Cc] row-major -> out: bf16 [Cc][R]
__global__ __launch_bounds__(256) void transpose_cast(const float* __restrict__ in,
                                                      unsigned short* __restrict__ out,
                                                      int R, int Cc) {
  __shared__ float tile[32][33];
  const int tx = threadIdx.x, ty = threadIdx.y;  // 32 x 8
  const int c0 = blockIdx.x * 32, r0 = blockIdx.y * 32;
  #pragma unroll
  for (int dy = 0; dy < 32; dy += 8)
    tile[ty + dy][tx] = in[(size_t)(r0 + ty + dy) * Cc + (c0 + tx)];
  __syncthreads();
  #pragma unroll
  for (int dy = 0; dy < 32; dy += 8)
    out[(size_t)(c0 + ty + dy) * R + (r0 + tx)] = f2bfu(tile[tx][ty + dy]);
}

// ---------------- 256x256 tile, BK=64, 4-phase MFMA GEMM (round-4 schedule) ----------
// MODE 0: QKV. Q/K blocks (n0<1024): LDS-transpose epilogue -> coalesced qkT writes.
//         V blocks (n0>=1024): direct vb[bh][n][d] stores (32-B chunked).
// MODE 1: proj -> f32 out + bias, row-major.
template <int MODE>
__global__ __launch_bounds__(512, 2) void gemm256(const unsigned short* __restrict__ A,
                                                  const unsigned short* __restrict__ Bt,
                                                  void* __restrict__ out0,
                                                  void* __restrict__ out1,
                                                  const float* __restrict__ bias,
                                                  int M, int Nn, int Kk, int nbx) {
  __shared__ __align__(16) char lds[131072];
  const int nwg = gridDim.x;
  int wg = blockIdx.x;
  wg = (wg & 7) * (nwg >> 3) + (wg >> 3);  // XCD swizzle (nwg % 8 == 0)
  const int bx = wg % nbx, by = wg / nbx;
  const int m0 = by * 256, n0 = bx * 256;

  const int tid = threadIdx.x, wave = tid >> 6, lane = tid & 63;
  const int wr = wave >> 2, wc = wave & 3;
  const int l15 = lane & 15, lg = lane >> 4;
  const int T = Kk >> 6;

  f32x4 acc[2][4][2][2] = {};
  short8 af[8], b0[4], b1[4];

  auto stageh = [&](int h, int kt, char* buf) {
    const bool isB = (h == 1 || h == 2);
    const unsigned short* src = isB ? Bt : A;
    const int rc0 = isB ? n0 : m0;
    const int rhalf = (h >= 2) ? 128 : 0;
    char* base = buf + (isB ? 32768 : 0);
    #pragma unroll
    for (int j = 0; j < 2; ++j) {
      const int rbase = rhalf + (wave * 2 + j) * 8;
      const unsigned short* g = src + (size_t)(rc0 + rbase + (lane >> 3)) * Kk + kt +
                                (((lane & 7) ^ (lane >> 3)) << 3);
      gload_lds16(g, base + rbase * 128);
    }
  };

  auto dsA = [&](int qa, const char* bufc) {
    #pragma unroll
    for (int fr = 0; fr < 4; ++fr)
      #pragma unroll
      for (int ks = 0; ks < 2; ++ks) {
        const int r = wr * 64 + qa * 128 + fr * 16 + l15;
        const int slot = ((ks << 2) + lg) ^ (r & 7);
        af[fr * 2 + ks] = *reinterpret_cast<const short8*>(bufc + r * 128 + (slot << 4));
      }
  };
  auto dsB = [&](int qb, const char* bufc, short8* bset) {
    #pragma unroll
    for (int fc = 0; fc < 2; ++fc)
      #pragma unroll
      for (int ks = 0; ks < 2; ++ks) {
        const int n = wc * 32 + qb * 128 + fc * 16 + l15;
        const int slot = ((ks << 2) + lg) ^ (n & 7);
        bset[fc * 2 + ks] =
            *reinterpret_cast<const short8*>(bufc + 32768 + n * 128 + (slot << 4));
      }
  };
  auto mfma16 = [&](int qa, int qb, const short8* bset) {
    __builtin_amdgcn_s_setprio(1);
    #pragma unroll
    for (int fr = 0; fr < 4; ++fr)
      #pragma unroll
      for (int fc = 0; fc < 2; ++fc)
        #pragma unroll
        for (int ks = 0; ks < 2; ++ks)
          acc[qa][fr][qb][fc] = __builtin_amdgcn_mfma_f32_16x16x32_bf16(
              af[fr * 2 + ks], bset[fc * 2 + ks], acc[qa][fr][qb][fc], 0, 0, 0);
    __builtin_amdgcn_s_setprio(0);
  };

  stageh(0, 0, lds); stageh(1, 0, lds); stageh(2, 0, lds); stageh(3, 0, lds);
  asm volatile("s_waitcnt vmcnt(0)" ::: "memory");
  __builtin_amdgcn_s_barrier();

  for (int t = 0; t < T - 1; ++t) {
    char* bufc = lds + ((t & 1) << 16);
    char* bufn = lds + (((t + 1) & 1) << 16);
    const int ktn = (t + 1) << 6;

    dsA(0, bufc);
    dsB(0, bufc, b0);
    stageh(0, ktn, bufn);
    stageh(1, ktn, bufn);
    __builtin_amdgcn_sched_barrier(0);
    asm volatile("s_waitcnt vmcnt(6)" ::: "memory");
    __builtin_amdgcn_s_barrier();
    asm volatile("s_waitcnt lgkmcnt(0)" ::: "memory");
    mfma16(0, 0, b0);
    __builtin_amdgcn_s_barrier();

    dsB(1, bufc, b1);
    stageh(2, ktn, bufn);
    __builtin_amdgcn_sched_barrier(0);
    asm volatile("s_waitcnt vmcnt(6)" ::: "memory");
    __builtin_amdgcn_s_barrier();
    asm volatile("s_waitcnt lgkmcnt(0)" ::: "memory");
    mfma16(0, 1, b1);
    __builtin_amdgcn_s_barrier();

    dsA(1, bufc);
    stageh(3, ktn, bufn);
    __builtin_amdgcn_sched_barrier(0);
    asm volatile("s_waitcnt vmcnt(8)" ::: "memory");
    __builtin_amdgcn_s_barrier();
    asm volatile("s_waitcnt lgkmcnt(0)" ::: "memory");
    mfma16(1, 1, b1);
    __builtin_amdgcn_s_barrier();

    asm volatile("s_waitcnt vmcnt(4)" ::: "memory");
    __builtin_amdgcn_s_barrier();
    mfma16(1, 0, b0);
    __builtin_amdgcn_s_barrier();
  }

  asm volatile("s_waitcnt vmcnt(0)" ::: "memory");
  __builtin_amdgcn_s_barrier();
  {
    const char* bufc = lds + (((T - 1) & 1) << 16);
    dsA(0, bufc);
    dsB(0, bufc, b0);
    asm volatile("s_waitcnt lgkmcnt(0)" ::: "memory");
    mfma16(0, 0, b0);
    dsB(1, bufc, b1);
    asm volatile("s_waitcnt lgkmcnt(0)" ::: "memory");
    mfma16(0, 1, b1);
    dsA(1, bufc);
    asm volatile("s_waitcnt lgkmcnt(0)" ::: "memory");
    mfma16(1, 1, b1);
    mfma16(1, 0, b0);
  }

  // ---------------- epilogue ----------------
  if (MODE == 1) {
    #pragma unroll
    for (int qa = 0; qa < 2; ++qa)
      #pragma unroll
      for (int fr = 0; fr < 4; ++fr)
        #pragma unroll
        for (int qb = 0; qb < 2; ++qb)
          #pragma unroll
          for (int fc = 0; fc < 2; ++fc) {
            const int row0 = m0 + wr * 64 + qa * 128 + fr * 16 + lg * 4;
            const int col = n0 + wc * 32 + qb * 128 + fc * 16 + l15;
            #pragma unroll
            for (int v = 0; v < 4; ++v)
              reinterpret_cast<float*>(out0)[(size_t)(row0 + v) * Nn + col] =
                  acc[qa][fr][qb][fc][v] + bias[col];
          }
  } else if (n0 < 1024) {
    // Q/K block: LDS-transpose then coalesced qkT stores.
    __builtin_amdgcn_s_barrier();  // all waves done reading K-loop LDS
    char* ldsb = lds;
    #pragma unroll
    for (int qa = 0; qa < 2; ++qa)
      #pragma unroll
      for (int fr = 0; fr < 4; ++fr)
        #pragma unroll
        for (int qb = 0; qb < 2; ++qb)
          #pragma unroll
          for (int fc = 0; fc < 2; ++fc) {
            const int nl = wr * 64 + qa * 128 + fr * 16 + lg * 4;   // token-local
            const int cl = wc * 32 + qb * 128 + fc * 16 + l15;     // col-local
            ushort4 o;
            o.x = f2bfu(acc[qa][fr][qb][fc][0]);
            o.y = f2bfu(acc[qa][fr][qb][fc][1]);
            o.z = f2bfu(acc[qa][fr][qb][fc][2]);
            o.w = f2bfu(acc[qa][fr][qb][fc][3]);
            const int byte = cl * 512 + ((nl * 2) ^ ((cl & 7) << 4));
            *reinterpret_cast<ushort4*>(ldsb + byte) = o;
          }
    __builtin_amdgcn_s_barrier();
    #pragma unroll
    for (int it = 0; it < 16; ++it) {
      const int cl = it * 16 + (tid >> 5);
      const int ns = (tid & 31) * 8;
      const int byte = cl * 512 + ((ns * 2) ^ ((cl & 7) << 4));
      short8 val = *reinterpret_cast<const short8*>(ldsb + byte);
      const int gcol = n0 + cl;
      const int sel = gcol >> 9, rem = gcol & 511;
      const int bh = (m0 >> 12) * 8 + (rem >> 6), cc = rem & 63;
      *reinterpret_cast<short8*>(&reinterpret_cast<unsigned short*>(out0)[
          ((size_t)sel * 4096 + bh * 64 + cc) * 4096 + (m0 & 4095) + ns]) = val;
    }
  } else {
    // V block: direct vb[bh][n][d] stores
    #pragma unroll
    for (int qa = 0; qa < 2; ++qa)
      #pragma unroll
      for (int fr = 0; fr < 4; ++fr)
        #pragma unroll
        for (int qb = 0; qb < 2; ++qb)
          #pragma unroll
          for (int fc = 0; fc < 2; ++fc) {
            const int row0 = m0 + wr * 64 + qa * 128 + fr * 16 + lg * 4;
            const int col = n0 + wc * 32 + qb * 128 + fc * 16 + l15;
            const int rem = col & 511, hh = rem >> 6, cc = rem & 63;
            const int bb = row0 >> 12, nseq = row0 & 4095;
            const int bh = bb * 8 + hh;
            #pragma unroll
            for (int v = 0; v < 4; ++v)
              reinterpret_cast<unsigned short*>(out1)[
                  ((size_t)bh * 4096 + nseq + v) * 64 + cc] =
                  f2bfu(acc[qa][fr][qb][fc][v]);
          }
  }
}

// ---------------- attn QK^T via MFMA: rawp[s][bh][c][d] partials + norms ----------------
// qkT: [sel][bh][c][n] bf16 (sel 0=Q,1=K), rows of 4096.
__global__ __launch_bounds__(256) void attn_qk(const unsigned short* __restrict__ qkT,
                                               float* __restrict__ rawp,
                                               float* __restrict__ normp) {
  const int bh = blockIdx.x, s = blockIdx.y;
  const int tid = threadIdx.x, w = tid >> 6, lane = tid & 63;
  const int l15 = lane & 15, lg = lane >> 4;
  const int nbase = s * 512 + w * 128;
  const unsigned short* qrow = qkT + (size_t)(bh * 64) * 4096;
  const unsigned short* krow = qkT + (size_t)(4096 + bh * 64) * 4096;

  __shared__ float red[4][64][64];
  __shared__ float nrm[4][2][64];

  f32x4 acc[4][4] = {};
  float sq[4] = {0.f, 0.f, 0.f, 0.f}, sk[4] = {0.f, 0.f, 0.f, 0.f};

  #pragma unroll
  for (int kc = 0; kc < 2; ++kc) {
    short8 aq[4][2], bk[4][2];
    #pragma unroll
    for (int fr = 0; fr < 4; ++fr)
      #pragma unroll
      for (int ks = 0; ks < 2; ++ks) {
        const size_t off = (size_t)(fr * 16 + l15) * 4096 + nbase + (kc * 2 + ks) * 32 + lg * 8;
        aq[fr][ks] = *reinterpret_cast<const short8*>(&qrow[off]);
        bk[fr][ks] = *reinterpret_cast<const short8*>(&krow[off]);
      }
    #pragma unroll
    for (int ks = 0; ks < 2; ++ks)
      #pragma unroll
      for (int fr = 0; fr < 4; ++fr)
        #pragma unroll
        for (int fc = 0; fc < 4; ++fc)
          acc[fr][fc] = __builtin_amdgcn_mfma_f32_16x16x32_bf16(
              aq[fr][ks], bk[fc][ks], acc[fr][fc], 0, 0, 0);
    #pragma unroll
    for (int fr = 0; fr < 4; ++fr)
      #pragma unroll
      for (int ks = 0; ks < 2; ++ks)
        #pragma unroll
        for (int j = 0; j < 8; ++j) {
          const float fq = bfu2f((unsigned short)aq[fr][ks][j]);
          const float fk = bfu2f((unsigned short)bk[fr][ks][j]);
          sq[fr] = fmaf(fq, fq, sq[fr]);
          sk[fr] = fmaf(fk, fk, sk[fr]);
        }
  }

  #pragma unroll
  for (int fr = 0; fr < 4; ++fr) {
    sq[fr] += __shfl_xor(sq[fr], 16); sq[fr] += __shfl_xor(sq[fr], 32);
    sk[fr] += __shfl_xor(sk[fr], 16); sk[fr] += __shfl_xor(sk[fr], 32);
  }
  if (lane < 16) {
    #pragma unroll
    for (int fr = 0; fr < 4; ++fr) {
      nrm[w][0][fr * 16 + lane] = sq[fr];
      nrm[w][1][fr * 16 + lane] = sk[fr];
    }
  }
  #pragma unroll
  for (int fr = 0; fr < 4; ++fr)
    #pragma unroll
    for (int fc = 0; fc < 4; ++fc)
      #pragma unroll
      for (int v = 0; v < 4; ++v)
        red[w][fr * 16 + lg * 4 + v][fc * 16 + l15] = acc[fr][fc][v];
  __syncthreads();

  const float* rf = &red[0][0][0];
  float* rp = rawp + ((size_t)s * 64 + bh) * 4096;
  for (int i = tid; i < 4096; i += 256)
    rp[i] = rf[i] + rf[4096 + i] + rf[8192 + i] + rf[12288 + i];
  const float* nf = &nrm[0][0][0];
  if (tid < 128) {
    float* np = normp + ((size_t)s * 64 + bh) * 128;
    np[tid] = nf[tid] + nf[128 + tid] + nf[256 + tid] + nf[384 + tid];
  }
}

// ---------------- finalize: reduce partials, normalize, softmax ----------------
__global__ __launch_bounds__(64) void attn_finalize(const float* __restrict__ rawp,
                                                    const float* __restrict__ normp,
                                                    const float* __restrict__ temperature,
                                                    unsigned short* __restrict__ attnP) {
  const int bh = blockIdx.x, c8 = blockIdx.y, h = bh & 7;
  const int d = threadIdx.x;
  float nq = 0.f, nk = 0.f;
  for (int s = 0; s < NSPL; ++s) {
    nq += normp[((size_t)s * 64 + bh) * 128 + d];
    nk += normp[((size_t)s * 64 + bh) * 128 + 64 + d];
  }
  nq = fmaxf(sqrtf(nq), 1e-12f);
  nk = fmaxf(sqrtf(nk), 1e-12f);
  const float t = temperature[h];
  for (int i = 0; i < 8; ++i) {
    const int c = c8 * 8 + i;
    float r = 0.f;
    for (int s = 0; s < NSPL; ++s)
      r += rawp[((size_t)s * 64 + bh) * 4096 + c * 64 + d];
    const float nqc = __shfl(nq, c);
    float v = r * t / (nqc * nk);
    float m = v;
    #pragma unroll
    for (int off = 32; off > 0; off >>= 1) m = fmaxf(m, __shfl_xor(m, off));
    float e = __expf(v - m);
    float ssum = e;
    #pragma unroll
    for (int off = 32; off > 0; off >>= 1) ssum += __shfl_xor(ssum, off);
    attnP[(size_t)bh * 4096 + c * 64 + d] = f2bfu(e / ssum);
  }
}

// ---------------- PV via MFMA: y[b*4096+n][h*64+c] = sum_d P[c,d] * vb[bh][n][d] --------
__global__ __launch_bounds__(256) void pv_mfma(const unsigned short* __restrict__ attnP,
                                               const unsigned short* __restrict__ vb,
                                               unsigned short* __restrict__ y) {
  const int nc = blockIdx.x, bh = blockIdx.y;
  const int b = bh >> 3, h = bh & 7;
  const int tid = threadIdx.x, w = tid >> 6, lane = tid & 63;
  const int l15 = lane & 15, lg = lane >> 4;
  const int n0 = nc * 256 + w * 64;

  short8 ap[4][2], bv[4][2];
  #pragma unroll
  for (int fr = 0; fr < 4; ++fr)
    #pragma unroll
    for (int ks = 0; ks < 2; ++ks)
      ap[fr][ks] = *reinterpret_cast<const short8*>(
          &attnP[(size_t)bh * 4096 + (fr * 16 + l15) * 64 + ks * 32 + lg * 8]);
  #pragma unroll
  for (int fc = 0; fc < 4; ++fc)
    #pragma unroll
    for (int ks = 0; ks < 2; ++ks)
      bv[fc][ks] = *reinterpret_cast<const short8*>(
          &vb[((size_t)bh * 4096 + n0 + fc * 16 + l15) * 64 + ks * 32 + lg * 8]);

  f32x4 acc[4][4] = {};
  #pragma unroll
  for (int ks = 0; ks < 2; ++ks)
    #pragma unroll
    for (int fr = 0; fr < 4; ++fr)
      #pragma unroll
      for (int fc = 0; fc < 4; ++fc)
        acc[fr][fc] = __builtin_amdgcn_mfma_f32_16x16x32_bf16(
            ap[fr][ks], bv[fc][ks], acc[fr][fc], 0, 0, 0);

  #pragma unroll
  for (int fr = 0; fr < 4; ++fr)
    #pragma unroll
    for (int fc = 0; fc < 4; ++fc) {
      const int n = n0 + fc * 16 + l15;
      const int c0 = fr * 16 + lg * 4;
      ushort4 o;
      o.x = f2bfu(acc[fr][fc][0]); o.y = f2bfu(acc[fr][fc][1]);
      o.z = f2bfu(acc[fr][fc][2]); o.w = f2bfu(acc[fr][fc][3]);
      *reinterpret_cast<ushort4*>(
          &y[((size_t)b * 4096 + n) * 512 + h * 64 + c0]) = o;
    }
}

extern "C" void kernel_launch(void* const* d_in, const int* in_sizes, int n_in,
                              void* d_out, int out_size, void* d_ws, size_t ws_size,
                              hipStream_t stream) {
  const float* x = (const float*)d_in[0];
  const float* Wqkv = (const float*)d_in[2];
  const float* temp = (const float*)d_in[3];
  const float* Wproj = (const float*)d_in[4];
  const float* bproj = (const float*)d_in[5];
  float* out = (float*)d_out;

  char* w = (char*)d_ws;
  unsigned short* xb = (unsigned short*)w;    w += (size_t)MTOK * CH * 2;
  unsigned short* wqT = (unsigned short*)w;   w += (size_t)K3C * CH * 2;
  unsigned short* wpT = (unsigned short*)w;   w += (size_t)CH * CH * 2;
  unsigned short* qkT = (unsigned short*)w;   w += (size_t)2 * 64 * 64 * 4096 * 2;
  unsigned short* vb = (unsigned short*)w;    w += (size_t)64 * 4096 * 64 * 2;
  unsigned short* yb = (unsigned short*)w;    w += (size_t)MTOK * CH * 2;
  float* rawp = (float*)w;                    w += (size_t)NSPL * 64 * 4096 * 4;
  float* normp = (float*)w;                   w += (size_t)NSPL * 64 * 128 * 4;
  unsigned short* attnP = (unsigned short*)w; w += (size_t)64 * 4096 * 2;

  cast_f32_bf16<<<2048, 256, 0, stream>>>(x, xb, MTOK * CH / 4);
  transpose_cast<<<dim3(K3C / 32, CH / 32), dim3(32, 8), 0, stream>>>(Wqkv, wqT, CH, K3C);
  transpose_cast<<<dim3(CH / 32, CH / 32), dim3(32, 8), 0, stream>>>(Wproj, wpT, CH, CH);
  gemm256<0><<<768, 512, 0, stream>>>(xb, wqT, qkT, vb, nullptr, MTOK, K3C, CH, 6);
  attn_qk<<<dim3(64, 8), 256, 0, stream>>>(qkT, rawp, normp);
  attn_finalize<<<dim3(64, 8), 64, 0, stream>>>(rawp, normp, temp, attnP);
  pv_mfma<<<dim3(16, 64), 256, 0, stream>>>(attnP, vb, yb);
  gemm256<1><<<256, 512, 0, stream>>>(yb, wpT, out, nullptr, bproj, MTOK, CH, CH, 2);
}